// Round 1
// baseline (85.320 us; speedup 1.0000x reference)
//
#include <hip/hip_runtime.h>

// Problem constants (from reference)
#define B_  64
#define T_  288
#define V_  24
#define D_  256
#define TOD_DIM 128
#define DOW_DIM 32
#define DOM_DIM 32
#define DOY_DIM 64

// One block per (b,t). 256 threads.
// Phase 1: build pos[256] in LDS from the 4 positional tables; stage feats[24].
// Phase 2: 24*64 = 1536 float4 outputs, 6 per thread, fully coalesced stores.
__global__ __launch_bounds__(256) void input_emb_kernel(
    const float* __restrict__ features,    // (B,T,V)
    const int*   __restrict__ bar_in_day,  // (B,T)
    const int*   __restrict__ day_of_week, // (B,)
    const int*   __restrict__ day_of_month,// (B,)
    const int*   __restrict__ day_of_year, // (B,)
    const float* __restrict__ W,           // (V,D)
    const float* __restrict__ bias,        // (V,D)
    const float* __restrict__ tod_table,   // (288,128)
    const float* __restrict__ dow_table,   // (7,32)
    const float* __restrict__ dom_table,   // (32,32)
    const float* __restrict__ doy_table,   // (367,64)
    float* __restrict__ out)               // (B,T,V,D)
{
    __shared__ __align__(16) float pos[D_];
    __shared__ float feats[V_];

    const int bt  = blockIdx.x;       // b*T + t
    const int b   = bt / T_;
    const int tid = threadIdx.x;

    // ---- Phase 1: compose positional vector for this (b,t) ----
    {
        const int d = tid;
        float p;
        if (d < TOD_DIM) {
            p = tod_table[bar_in_day[bt] * TOD_DIM + d];
        } else if (d < TOD_DIM + DOW_DIM) {
            p = dow_table[day_of_week[b] * DOW_DIM + (d - TOD_DIM)];
        } else if (d < TOD_DIM + DOW_DIM + DOM_DIM) {
            p = dom_table[day_of_month[b] * DOM_DIM + (d - TOD_DIM - DOW_DIM)];
        } else {
            p = doy_table[day_of_year[b] * DOY_DIM + (d - TOD_DIM - DOW_DIM - DOM_DIM)];
        }
        pos[d] = p;
    }
    if (tid < V_) feats[tid] = features[bt * V_ + tid];
    __syncthreads();

    // ---- Phase 2: fan out to (V, D) ----
    float* outbt = out + (size_t)bt * (V_ * D_);

    #pragma unroll
    for (int it = 0; it < (V_ * D_ / 4) / 256; ++it) {   // 6 iterations
        const int idx = it * 256 + tid;     // float4 index within (V,D)
        const int v   = idx >> 6;           // idx / 64  (wave-uniform)
        const int d4  = idx & 63;           // float4 column

        const float x = feats[v];
        const float4 w4 = *reinterpret_cast<const float4*>(W    + (v << 8) + (d4 << 2));
        const float4 b4 = *reinterpret_cast<const float4*>(bias + (v << 8) + (d4 << 2));
        const float4 p4 = *reinterpret_cast<const float4*>(&pos[d4 << 2]);

        float4 o;
        o.x = fmaf(x, w4.x, b4.x) + p4.x;
        o.y = fmaf(x, w4.y, b4.y) + p4.y;
        o.z = fmaf(x, w4.z, b4.z) + p4.z;
        o.w = fmaf(x, w4.w, b4.w) + p4.w;

        *reinterpret_cast<float4*>(outbt + (idx << 2)) = o;
    }
}

extern "C" void kernel_launch(void* const* d_in, const int* in_sizes, int n_in,
                              void* d_out, int out_size, void* d_ws, size_t ws_size,
                              hipStream_t stream) {
    const float* features     = (const float*)d_in[0];
    const int*   bar_in_day   = (const int*)d_in[1];
    const int*   day_of_week  = (const int*)d_in[2];
    const int*   day_of_month = (const int*)d_in[3];
    const int*   day_of_year  = (const int*)d_in[4];
    const float* W            = (const float*)d_in[5];
    const float* bias         = (const float*)d_in[6];
    const float* tod_table    = (const float*)d_in[7];
    const float* dow_table    = (const float*)d_in[8];
    const float* dom_table    = (const float*)d_in[9];
    const float* doy_table    = (const float*)d_in[10];
    float* out = (float*)d_out;

    dim3 grid(B_ * T_);
    dim3 block(256);
    input_emb_kernel<<<grid, block, 0, stream>>>(
        features, bar_in_day, day_of_week, day_of_month, day_of_year,
        W, bias, tod_table, dow_table, dom_table, doy_table, out);
}